// Round 10
// baseline (420.947 us; speedup 1.0000x reference)
//
#include <hip/hip_runtime.h>

#define B_  2
#define L_  2048
#define D_  1024
#define DI_ 2048
#define NS  16
#define RR  64
#define MM  (B_*L_)      // 4096 rows
#define NC  64           // scan chunks
#define CL  (L_/NC)      // 32 steps per chunk
#define XKS 8            // xproj split-K slices

typedef __attribute__((ext_vector_type(8))) short bf16x8;
typedef __attribute__((ext_vector_type(4))) float f32x4;

__device__ __forceinline__ ushort f2bf_rn(float f) {
    union { float f; unsigned u; } v; v.f = f;
    unsigned r = v.u + 0x7FFF + ((v.u >> 16) & 1);
    return (ushort)(r >> 16);
}
__device__ __forceinline__ float bf2f(ushort h) {
    union { unsigned u; float f; } v; v.u = ((unsigned)h) << 16;
    return v.f;
}
__device__ __forceinline__ void gload_lds16(const ushort* g, ushort* l) {
    __builtin_amdgcn_global_load_lds(
        (const __attribute__((address_space(1))) void*)(g),
        (__attribute__((address_space(3))) void*)(l), 16, 0, 0);
}

// ---------------------------------------------------------------------------
// cvt: fp32 -> bf16 hi/lo pair (elementwise, n multiple of 4)
// ---------------------------------------------------------------------------
__global__ __launch_bounds__(256)
void cvt_hilo(const float* __restrict__ in, ushort* __restrict__ hi,
              ushort* __restrict__ lo, int n4)
{
    int i = blockIdx.x * 256 + threadIdx.x;
    if (i >= n4) return;
    float4 v = ((const float4*)in)[i];
    ushort4 h, l;
    h.x = f2bf_rn(v.x); l.x = f2bf_rn(v.x - bf2f(h.x));
    h.y = f2bf_rn(v.y); l.y = f2bf_rn(v.y - bf2f(h.y));
    h.z = f2bf_rn(v.z); l.z = f2bf_rn(v.z - bf2f(h.z));
    h.w = f2bf_rn(v.w); l.w = f2bf_rn(v.w - bf2f(h.w));
    ((ushort4*)hi)[i] = h; ((ushort4*)lo)[i] = l;
}

// ---------------------------------------------------------------------------
// C[M,N] = A@W^T (+bias) via bf16x3: hi*hi + hi*lo + lo*hi, fp32 accum.
// BK=64, LDS 4 x [128][64] ushort = 64 KB, 2 blocks/CU, 96 MFMA/wave/step.
// Rule-21 both-sides XOR swizzle: stage source k-slot = s ^ (row&7)
// (gload_lds writes linearly); read slot = ks ^ (row&7).
// gridDim.z = split-K; partial z writes C + z*MM*N.
// ---------------------------------------------------------------------------
__global__ __launch_bounds__(256, 2)
void gemm_bf16x3(const ushort* __restrict__ Ah, const ushort* __restrict__ Al,
                 const ushort* __restrict__ Bh, const ushort* __restrict__ Bl,
                 const float* __restrict__ bias, float* __restrict__ C,
                 int lda, int N, int kPerSplit)
{
    __shared__ ushort sAh[128*64], sAl[128*64], sBh[128*64], sBl[128*64];
    const int t    = threadIdx.x;
    const int bm   = blockIdx.y * 128, bn = blockIdx.x * 128;
    const int lane = t & 63, w = t >> 6;
    const int wr   = (w >> 1) * 64, wc = (w & 1) * 64;
    const int l16  = lane & 15;
    const int kbeg = blockIdx.z * kPerSplit;
    C += (size_t)blockIdx.z * MM * N;

    // staging: wave w covers rows [w*32, w*32+32); per call j: rows +j*8
    const int srow    = w * 32 + (lane >> 3);
    const int srcslot = (lane & 7) ^ ((lane >> 3) & 7);  // inverse swizzle
    const ushort* gAh = Ah + (size_t)(bm + srow) * lda + srcslot * 8 + kbeg;
    const ushort* gAl = Al + (size_t)(bm + srow) * lda + srcslot * 8 + kbeg;
    const ushort* gBh = Bh + (size_t)(bn + srow) * lda + srcslot * 8 + kbeg;
    const ushort* gBl = Bl + (size_t)(bn + srow) * lda + srcslot * 8 + kbeg;
    ushort* lAh = sAh + 2048 * w;   // wave-uniform LDS bases (+ j*512)
    ushort* lAl = sAl + 2048 * w;
    ushort* lBh = sBh + 2048 * w;
    ushort* lBl = sBl + 2048 * w;

    f32x4 acc[4][4];
    #pragma unroll
    for (int i = 0; i < 4; ++i)
        #pragma unroll
        for (int j = 0; j < 4; ++j)
            acc[i][j] = (f32x4){0.f, 0.f, 0.f, 0.f};

    for (int k0 = 0; k0 < kPerSplit; k0 += 64) {
        #pragma unroll
        for (int j = 0; j < 4; ++j) {
            const size_t go = (size_t)j * 8 * lda + k0;
            gload_lds16(gAh + go, lAh + j * 512);
            gload_lds16(gAl + go, lAl + j * 512);
            gload_lds16(gBh + go, lBh + j * 512);
            gload_lds16(gBl + go, lBl + j * 512);
        }
        __syncthreads();
        #pragma unroll
        for (int sub = 0; sub < 2; ++sub) {
            const int ks  = (sub << 2) | (lane >> 4);        // k-slot 0..7
            const int ssw = ks ^ (l16 & 7);                  // swizzled slot
            bf16x8 fbh[4], fbl[4];
            #pragma unroll
            for (int nj = 0; nj < 4; ++nj) {
                int off = (wc + nj * 16 + l16) * 64 + ssw * 8;
                fbh[nj] = *(const bf16x8*)(sBh + off);
                fbl[nj] = *(const bf16x8*)(sBl + off);
            }
            #pragma unroll
            for (int mi = 0; mi < 4; ++mi) {
                int off = (wr + mi * 16 + l16) * 64 + ssw * 8;
                bf16x8 fah = *(const bf16x8*)(sAh + off);
                bf16x8 fal = *(const bf16x8*)(sAl + off);
                #pragma unroll
                for (int nj = 0; nj < 4; ++nj) {
                    acc[mi][nj] = __builtin_amdgcn_mfma_f32_16x16x32_bf16(fah, fbh[nj], acc[mi][nj], 0, 0, 0);
                    acc[mi][nj] = __builtin_amdgcn_mfma_f32_16x16x32_bf16(fah, fbl[nj], acc[mi][nj], 0, 0, 0);
                    acc[mi][nj] = __builtin_amdgcn_mfma_f32_16x16x32_bf16(fal, fbh[nj], acc[mi][nj], 0, 0, 0);
                }
            }
        }
        __syncthreads();
    }
    // C/D layout: col = lane&15, row = (lane>>4)*4 + reg  [m89-verified]
    #pragma unroll
    for (int nj = 0; nj < 4; ++nj) {
        int col = bn + wc + nj * 16 + l16;
        float bb = bias ? bias[col] : 0.f;
        #pragma unroll
        for (int mi = 0; mi < 4; ++mi) {
            int row0 = bm + wr + mi * 16 + (lane >> 4) * 4;
            #pragma unroll
            for (int r = 0; r < 4; ++r)
                C[(size_t)(row0 + r) * N + col] = acc[mi][nj][r] + bb;
        }
    }
}

// ---------------------------------------------------------------------------
// out[M,D] = part0 + part1 + bias   (split-K combine for gemm2)
// ---------------------------------------------------------------------------
__global__ __launch_bounds__(256)
void combine2(const float* __restrict__ part, const float* __restrict__ ob,
              float* __restrict__ out)
{
    int i = blockIdx.x * 256 + threadIdx.x;        // MM*D_/4
    float4 a = ((const float4*)part)[i];
    float4 b = ((const float4*)(part + (size_t)MM * D_))[i];
    float4 bb = *(const float4*)(ob + ((i & (D_/4 - 1)) << 2));
    float4 o;
    o.x = a.x + b.x + bb.x; o.y = a.y + b.y + bb.y;
    o.z = a.z + b.z + bb.z; o.w = a.w + b.w + bb.w;
    ((float4*)out)[i] = o;
}

// ---------------------------------------------------------------------------
// u = silu(depthwise_conv3(h) + conv_b)  — float4-vectorized along di
// ---------------------------------------------------------------------------
__global__ __launch_bounds__(256)
void conv_silu(const float* __restrict__ h, const float* __restrict__ cw,
               const float* __restrict__ cb, float* __restrict__ u)
{
    size_t i4 = ((size_t)blockIdx.x * 256 + threadIdx.x) << 2;   // elem index
    int    di = (int)(i4 & (DI_ - 1));
    int    l  = (int)((i4 >> 11) & (L_ - 1));
    float4 cc = *(const float4*)(h + i4);
    float4 lf = make_float4(0.f, 0.f, 0.f, 0.f);
    float4 rt = make_float4(0.f, 0.f, 0.f, 0.f);
    if (l > 0)      lf = *(const float4*)(h + i4 - DI_);
    if (l < L_ - 1) rt = *(const float4*)(h + i4 + DI_);
    float4 bb = *(const float4*)(cb + di);
    float cin[4]  = {cc.x, cc.y, cc.z, cc.w};
    float lin[4]  = {lf.x, lf.y, lf.z, lf.w};
    float rin[4]  = {rt.x, rt.y, rt.z, rt.w};
    float bin[4]  = {bb.x, bb.y, bb.z, bb.w};
    float res[4];
    #pragma unroll
    for (int j = 0; j < 4; ++j) {
        const float* w = cw + (size_t)(di + j) * 3;
        float s = bin[j] + lin[j] * w[0] + cin[j] * w[1] + rin[j] * w[2];
        res[j] = s / (1.f + __expf(-s));
    }
    *(float4*)(u + i4) = make_float4(res[0], res[1], res[2], res[3]);
}

// ---------------------------------------------------------------------------
// xproj stage A: partial[s][m][c] = sum_{k in slice s} u[m][k]*xw[c][k]
// ---------------------------------------------------------------------------
__global__ __launch_bounds__(256)
void xprojA(const float* __restrict__ u, const float* __restrict__ xw,
            float* __restrict__ part)
{
    __shared__ float ut[32][132];
    __shared__ float wt[80][132];
    const int t  = threadIdx.x;
    const int bm = blockIdx.x * 32;
    const int ks = blockIdx.y;
    const int r2 = t & 15, cg = t >> 4;
    float acc[2][5] = {};
    for (int ch = 0; ch < 2; ++ch) {
        const int kb = ks * 256 + ch * 128;
        {
            int sr = t >> 3, k4 = (t & 7) * 4;
            #pragma unroll
            for (int i = 0; i < 4; ++i) {
                float4 v = *(const float4*)(u + (size_t)(bm + sr) * DI_ + kb + k4 + 32 * i);
                ut[sr][k4 + 32*i + 0] = v.x; ut[sr][k4 + 32*i + 1] = v.y;
                ut[sr][k4 + 32*i + 2] = v.z; ut[sr][k4 + 32*i + 3] = v.w;
            }
        }
        #pragma unroll
        for (int i = 0; i < 10; ++i) {
            int idx = t + 256 * i;
            int wrow = idx >> 5, k4 = (idx & 31) * 4;
            float4 v = *(const float4*)(xw + (size_t)wrow * DI_ + kb + k4);
            wt[wrow][k4 + 0] = v.x; wt[wrow][k4 + 1] = v.y;
            wt[wrow][k4 + 2] = v.z; wt[wrow][k4 + 3] = v.w;
        }
        __syncthreads();
        for (int k = 0; k < 128; k += 4) {
            float4 u0 = *(const float4*)&ut[r2][k];
            float4 u1 = *(const float4*)&ut[r2 + 16][k];
            #pragma unroll
            for (int c = 0; c < 5; ++c) {
                float4 wv = *(const float4*)&wt[cg * 5 + c][k];
                acc[0][c] = fmaf(u0.x, wv.x, fmaf(u0.y, wv.y, fmaf(u0.z, wv.z, fmaf(u0.w, wv.w, acc[0][c]))));
                acc[1][c] = fmaf(u1.x, wv.x, fmaf(u1.y, wv.y, fmaf(u1.z, wv.z, fmaf(u1.w, wv.w, acc[1][c]))));
            }
        }
        __syncthreads();
    }
    size_t b0 = ((size_t)ks * MM + bm + r2) * 80 + cg * 5;
    size_t b1 = ((size_t)ks * MM + bm + r2 + 16) * 80 + cg * 5;
    #pragma unroll
    for (int c = 0; c < 5; ++c) { part[b0 + c] = acc[0][c]; part[b1 + c] = acc[1][c]; }
}

__global__ __launch_bounds__(256)
void xprojB(const float* __restrict__ part, const float* __restrict__ xpb,
            float* __restrict__ xdbl)
{
    int idx = blockIdx.x * 256 + threadIdx.x;   // MM*80
    int c = idx % 80;
    float s = xpb[c];
    #pragma unroll
    for (int sl = 0; sl < XKS; ++sl)
        s += part[(size_t)sl * (MM * 80) + idx];
    xdbl[idx] = s;
}

__global__ __launch_bounds__(256)
void transpose_dtw(const float* __restrict__ dtw, float* __restrict__ dtwT)
{
    int idx = blockIdx.x * 256 + threadIdx.x;   // RR*DI
    int di  = idx & (DI_ - 1);
    int r   = idx >> 11;
    dtwT[(size_t)r * DI_ + di] = dtw[(size_t)di * RR + r];
}

// ---------------------------------------------------------------------------
// delta[M,DI] = softplus(xdbl[:, :64] @ dtwT + dt_b)
// ---------------------------------------------------------------------------
__global__ __launch_bounds__(256)
void delta_gemm(const float* __restrict__ xdbl, const float* __restrict__ dtwT,
                const float* __restrict__ dtb, float* __restrict__ delta)
{
    __shared__ float dl[16][64];
    const int t    = threadIdx.x;
    const int row0 = blockIdx.y * 16;
    const int col  = blockIdx.x * 256 + t;
    {
        int sr = t >> 4, sk = (t & 15) << 2;
        float4 v = *(const float4*)(xdbl + (size_t)(row0 + sr) * 80 + sk);
        dl[sr][sk] = v.x; dl[sr][sk+1] = v.y; dl[sr][sk+2] = v.z; dl[sr][sk+3] = v.w;
    }
    __syncthreads();
    float acc[16] = {};
    for (int k = 0; k < 64; ++k) {
        float w = dtwT[(size_t)k * DI_ + col];
        #pragma unroll
        for (int rr = 0; rr < 16; ++rr)
            acc[rr] = fmaf(dl[rr][k], w, acc[rr]);
    }
    float bias = dtb[col];
    #pragma unroll
    for (int rr = 0; rr < 16; ++rr) {
        float x  = acc[rr] + bias;
        float sp = fmaxf(x, 0.f) + log1pf(__expf(-fabsf(x)));
        delta[(size_t)(row0 + rr) * DI_ + col] = sp;
    }
}

// ---------------------------------------------------------------------------
// Scan pass A (2 threads per (b,ch,di): 8 states each, 8 waves/SIMD)
// ---------------------------------------------------------------------------
__global__ __launch_bounds__(256)
void scanA(const float* __restrict__ delta, const float* __restrict__ u,
           const float* __restrict__ xdbl, const float* __restrict__ A_log,
           float* __restrict__ Pbuf, float* __restrict__ Sbuf)
{
    const int tid  = blockIdx.x * 256 + threadIdx.x;   // B*NC*DI*2
    const int half = tid & 1;
    const int di   = (tid >> 1) & (DI_ - 1);
    const int rest = tid >> 12;
    const int ch   = rest & (NC - 1);
    const int b    = rest >> 6;
    float A2[8];
    {
        const float4* ap = (const float4*)(A_log + (size_t)di * NS + half * 8);
        #pragma unroll
        for (int q = 0; q < 2; ++q) {
            float4 v = ap[q];
            A2[q*4+0] = -__expf(v.x) * 1.44269504f;
            A2[q*4+1] = -__expf(v.y) * 1.44269504f;
            A2[q*4+2] = -__expf(v.z) * 1.44269504f;
            A2[q*4+3] = -__expf(v.w) * 1.44269504f;
        }
    }
    float c[8], P[8];
    #pragma unroll
    for (int n = 0; n < 8; ++n) { c[n] = 0.f; P[n] = 1.f; }
    const size_t l0 = (size_t)b * L_ + (size_t)ch * CL;
    const float* dp = delta + l0 * DI_ + di;
    const float* up = u     + l0 * DI_ + di;
    const float* xp = xdbl  + l0 * 80 + RR + half * 8;
    for (int l = 0; l < CL; ++l) {
        float dlt = dp[(size_t)l * DI_];
        float du  = dlt * up[(size_t)l * DI_];
        const float4* bp = (const float4*)(xp + (size_t)l * 80);
        #pragma unroll
        for (int q = 0; q < 2; ++q) {
            float4 bv = bp[q];
            float bn_[4] = {bv.x, bv.y, bv.z, bv.w};
            #pragma unroll
            for (int j = 0; j < 4; ++j) {
                int   n = q * 4 + j;
                float a = exp2f(dlt * A2[n]);
                c[n] = fmaf(a, c[n], du * bn_[j]);
                P[n] *= a;
            }
        }
    }
    const size_t base = ((size_t)(b * NC + ch) * DI_ + di) * NS + half * 8;
    float4* Pp = (float4*)(Pbuf + base);
    float4* Sp = (float4*)(Sbuf + base);
    #pragma unroll
    for (int q = 0; q < 2; ++q) {
        Pp[q] = make_float4(P[q*4], P[q*4+1], P[q*4+2], P[q*4+3]);
        Sp[q] = make_float4(c[q*4], c[q*4+1], c[q*4+2], c[q*4+3]);
    }
}

__global__ __launch_bounds__(256)
void scanB(const float* __restrict__ Pbuf, const float* __restrict__ Sbuf,
           float* __restrict__ start)
{
    const int tid = blockIdx.x * 256 + threadIdx.x;   // B*DI*NS
    const int n   = tid & (NS - 1);
    const int di  = (tid >> 4) & (DI_ - 1);
    const int b   = tid >> 15;
    float c = 0.f;
    for (int ch = 0; ch < NC; ++ch) {
        size_t idx = ((size_t)(b * NC + ch) * DI_ + di) * NS + n;
        start[idx] = c;
        c = fmaf(Pbuf[idx], c, Sbuf[idx]);
    }
}

// ---------------------------------------------------------------------------
// Scan pass C (2 threads per (b,ch,di)): replay; pairwise shfl for the state
// sum; half 0 writes y as bf16 hi/lo.
// ---------------------------------------------------------------------------
__global__ __launch_bounds__(256)
void scanC(const float* __restrict__ delta, const float* __restrict__ u,
           const float* __restrict__ xdbl, const float* __restrict__ A_log,
           const float* __restrict__ Dp, const float* __restrict__ start,
           ushort* __restrict__ yh, ushort* __restrict__ yl)
{
    const int tid  = blockIdx.x * 256 + threadIdx.x;   // B*NC*DI*2
    const int half = tid & 1;
    const int di   = (tid >> 1) & (DI_ - 1);
    const int rest = tid >> 12;
    const int ch   = rest & (NC - 1);
    const int b    = rest >> 6;
    float A2[8];
    {
        const float4* ap = (const float4*)(A_log + (size_t)di * NS + half * 8);
        #pragma unroll
        for (int q = 0; q < 2; ++q) {
            float4 v = ap[q];
            A2[q*4+0] = -__expf(v.x) * 1.44269504f;
            A2[q*4+1] = -__expf(v.y) * 1.44269504f;
            A2[q*4+2] = -__expf(v.z) * 1.44269504f;
            A2[q*4+3] = -__expf(v.w) * 1.44269504f;
        }
    }
    float c[8];
    {
        const size_t base = ((size_t)(b * NC + ch) * DI_ + di) * NS + half * 8;
        const float4* sp = (const float4*)(start + base);
        #pragma unroll
        for (int q = 0; q < 2; ++q) {
            float4 v = sp[q];
            c[q*4+0] = v.x; c[q*4+1] = v.y; c[q*4+2] = v.z; c[q*4+3] = v.w;
        }
    }
    const float Dpar = Dp[di];
    const size_t l0 = (size_t)b * L_ + (size_t)ch * CL;
    const float* dp = delta + l0 * DI_ + di;
    const float* up = u     + l0 * DI_ + di;
    const float* xp = xdbl  + l0 * 80 + RR + half * 8;
    for (int l = 0; l < CL; ++l) {
        float dlt = dp[(size_t)l * DI_];
        float uu  = up[(size_t)l * DI_];
        float du  = dlt * uu;
        const float4* bp = (const float4*)(xp + (size_t)l * 80);
        float sum = 0.f;
        #pragma unroll
        for (int q = 0; q < 2; ++q) {
            float4 bv = bp[q];
            float bn_[4] = {bv.x, bv.y, bv.z, bv.w};
            #pragma unroll
            for (int j = 0; j < 4; ++j) {
                int   n = q * 4 + j;
                float a = exp2f(dlt * A2[n]);
                c[n] = fmaf(a, c[n], du * bn_[j]);
                sum += c[n];
            }
        }
        float tot = sum + __shfl_xor(sum, 1);       // partner has other 8 states
        if (!half) {
            float y = tot + uu * Dpar;
            ushort hb = f2bf_rn(y);
            size_t oi = (l0 + l) * DI_ + di;
            yh[oi] = hb;
            yl[oi] = f2bf_rn(y - bf2f(hb));
        }
    }
}

// ---------------------------------------------------------------------------
extern "C" void kernel_launch(void* const* d_in, const int* in_sizes, int n_in,
                              void* d_out, int out_size, void* d_ws, size_t ws_size,
                              hipStream_t stream)
{
    const float* x      = (const float*)d_in[0];
    const float* in_w   = (const float*)d_in[1];
    const float* in_b   = (const float*)d_in[2];
    const float* conv_w = (const float*)d_in[3];
    const float* conv_b = (const float*)d_in[4];
    const float* xpw    = (const float*)d_in[5];
    const float* xpb    = (const float*)d_in[6];
    const float* dt_w   = (const float*)d_in[7];
    const float* dt_b   = (const float*)d_in[8];
    const float* A_log  = (const float*)d_in[9];
    const float* Dpar   = (const float*)d_in[10];
    const float* out_w  = (const float*)d_in[11];
    const float* out_b  = (const float*)d_in[12];
    float*       out    = (float*)d_out;

    char* ws  = (char*)d_ws;
    size_t off = 0;
    auto alloc = [&](size_t bytes) {
        void* p = ws + off; off = (off + bytes + 255) & ~(size_t)255; return p;
    };
    float*  u_    = (float*)alloc((size_t)MM * DI_ * 4);   // u; later gemm2 partials
    float*  h_    = (float*)alloc((size_t)MM * DI_ * 4);   // h -> delta
    float*  xdbl  = (float*)alloc((size_t)MM * 80 * 4);
    float*  dtwT  = (float*)alloc((size_t)RR * DI_ * 4);
    ushort* yh    = (ushort*)alloc((size_t)MM * DI_ * 2);  // aliases: xpart, Pbuf (16.8MB)
    ushort* yl    = (ushort*)alloc((size_t)MM * DI_ * 2);  // aliases: Sbuf (16.8MB)
    ushort* xh    = (ushort*)alloc((size_t)MM * D_ * 2);   // dead after gemm1
    ushort* xl    = (ushort*)alloc((size_t)MM * D_ * 2);   //   -> stbuf aliases xh+xl
    ushort* wih   = (ushort*)alloc((size_t)DI_ * D_ * 2);
    ushort* wil   = (ushort*)alloc((size_t)DI_ * D_ * 2);
    ushort* woh   = (ushort*)alloc((size_t)D_ * DI_ * 2);
    ushort* wol   = (ushort*)alloc((size_t)D_ * DI_ * 2);
    float*  xpart = (float*)yh;     // 10.5 MB <= 16.8 MB
    float*  Pbuf  = (float*)yh;     // NC=64: B*NC*DI*NS*4 = 16.8 MB (exact fit)
    float*  Sbuf  = (float*)yl;
    float*  stbuf = (float*)xh;     // 16.8 MB spans xh+xl (both dead after gemm1)
    float*  part2 = u_;             // gemm2 split-K partials (2x16.8 = 33.6 MB)

    // 0. bf16 hi/lo conversions
    cvt_hilo<<<(MM * D_ / 4 + 255) / 256, 256, 0, stream>>>(x, xh, xl, MM * D_ / 4);
    cvt_hilo<<<(DI_ * D_ / 4 + 255) / 256, 256, 0, stream>>>(in_w, wih, wil, DI_ * D_ / 4);
    cvt_hilo<<<(D_ * DI_ / 4 + 255) / 256, 256, 0, stream>>>(out_w, woh, wol, D_ * DI_ / 4);
    // 1. h = x @ in_w^T + in_b   [4096 x 2048], K=1024 (16 K-steps of 64)
    gemm_bf16x3<<<dim3(DI_ / 128, MM / 128, 1), 256, 0, stream>>>(
        xh, xl, wih, wil, in_b, h_, D_, DI_, D_);
    // 2. u = silu(conv3(h) + conv_b)
    conv_silu<<<(MM * DI_ / 4) / 256, 256, 0, stream>>>(h_, conv_w, conv_b, u_);
    // 3. x_dbl = u @ x_proj_w^T + x_proj_b  (split-K two-stage)
    xprojA<<<dim3(MM / 32, XKS), 256, 0, stream>>>(u_, xpw, xpart);
    xprojB<<<(MM * 80) / 256, 256, 0, stream>>>(xpart, xpb, xdbl);
    // 4. dt_w transpose
    transpose_dtw<<<(RR * DI_) / 256, 256, 0, stream>>>(dt_w, dtwT);
    // 5. delta = softplus(delta_lr @ dt_w^T + dt_b)  -> h_
    delta_gemm<<<dim3(DI_ / 256, MM / 16), 256, 0, stream>>>(xdbl, dtwT, dt_b, h_);
    // 6-8. chunked selective scan (NC=64, 2 threads/di); y as bf16 hi/lo
    scanA<<<(B_ * NC * DI_ * 2) / 256, 256, 0, stream>>>(h_, u_, xdbl, A_log, Pbuf, Sbuf);
    scanB<<<(B_ * DI_ * NS) / 256, 256, 0, stream>>>(Pbuf, Sbuf, stbuf);
    scanC<<<(B_ * NC * DI_ * 2) / 256, 256, 0, stream>>>(h_, u_, xdbl, A_log, Dpar, stbuf, yh, yl);
    // 9. out = y @ out_w^T + out_b  [4096 x 1024], K=2048, split-K=2 (16 K-steps)
    gemm_bf16x3<<<dim3(D_ / 128, MM / 128, 2), 256, 0, stream>>>(
        yh, yl, woh, wol, nullptr, part2, DI_, D_, DI_ / 2);
    combine2<<<(MM * D_ / 4) / 256, 256, 0, stream>>>(part2, out_b, out);
}

// Round 11
// 404.414 us; speedup vs baseline: 1.0409x; 1.0409x over previous
//
#include <hip/hip_runtime.h>

#define B_  2
#define L_  2048
#define D_  1024
#define DI_ 2048
#define NS  16
#define RR  64
#define MM  (B_*L_)      // 4096 rows
#define NC  64           // scan chunks
#define CL  (L_/NC)      // 32 steps per chunk
#define XKS 8            // xproj split-K slices

typedef __attribute__((ext_vector_type(8))) short bf16x8;
typedef __attribute__((ext_vector_type(4))) float f32x4;

__device__ __forceinline__ ushort f2bf_rn(float f) {
    union { float f; unsigned u; } v; v.f = f;
    unsigned r = v.u + 0x7FFF + ((v.u >> 16) & 1);
    return (ushort)(r >> 16);
}
__device__ __forceinline__ float bf2f(ushort h) {
    union { unsigned u; float f; } v; v.u = ((unsigned)h) << 16;
    return v.f;
}
__device__ __forceinline__ void gload_lds16(const ushort* g, ushort* l) {
    __builtin_amdgcn_global_load_lds(
        (const __attribute__((address_space(1))) void*)(g),
        (__attribute__((address_space(3))) void*)(l), 16, 0, 0);
}

// ---------------------------------------------------------------------------
// cvt: fp32 -> bf16 hi/lo pair (elementwise, n multiple of 4)
// ---------------------------------------------------------------------------
__global__ __launch_bounds__(256)
void cvt_hilo(const float* __restrict__ in, ushort* __restrict__ hi,
              ushort* __restrict__ lo, int n4)
{
    int i = blockIdx.x * 256 + threadIdx.x;
    if (i >= n4) return;
    float4 v = ((const float4*)in)[i];
    ushort4 h, l;
    h.x = f2bf_rn(v.x); l.x = f2bf_rn(v.x - bf2f(h.x));
    h.y = f2bf_rn(v.y); l.y = f2bf_rn(v.y - bf2f(h.y));
    h.z = f2bf_rn(v.z); l.z = f2bf_rn(v.z - bf2f(h.z));
    h.w = f2bf_rn(v.w); l.w = f2bf_rn(v.w - bf2f(h.w));
    ((ushort4*)hi)[i] = h; ((ushort4*)lo)[i] = l;
}

// ---------------------------------------------------------------------------
// C[M,N] = A@W^T (+bias) via bf16x3: hi*hi + hi*lo + lo*hi, fp32 accum.
// BK=64, LDS 4 x [128][64] ushort = 64 KB, 2 blocks/CU, 96 MFMA/wave/step.
// Rule-21 both-sides XOR swizzle: stage source k-slot = s ^ (row&7)
// (gload_lds writes linearly); read slot = ks ^ (row&7).
// gridDim.z = split-K; partial z writes C + z*MM*N.
// ---------------------------------------------------------------------------
__global__ __launch_bounds__(256, 2)
void gemm_bf16x3(const ushort* __restrict__ Ah, const ushort* __restrict__ Al,
                 const ushort* __restrict__ Bh, const ushort* __restrict__ Bl,
                 const float* __restrict__ bias, float* __restrict__ C,
                 int lda, int N, int kPerSplit)
{
    __shared__ ushort sAh[128*64], sAl[128*64], sBh[128*64], sBl[128*64];
    const int t    = threadIdx.x;
    const int bm   = blockIdx.y * 128, bn = blockIdx.x * 128;
    const int lane = t & 63, w = t >> 6;
    const int wr   = (w >> 1) * 64, wc = (w & 1) * 64;
    const int l16  = lane & 15;
    const int kbeg = blockIdx.z * kPerSplit;
    C += (size_t)blockIdx.z * MM * N;

    // staging: wave w covers rows [w*32, w*32+32); per call j: rows +j*8
    const int srow    = w * 32 + (lane >> 3);
    const int srcslot = (lane & 7) ^ ((lane >> 3) & 7);  // inverse swizzle
    const ushort* gAh = Ah + (size_t)(bm + srow) * lda + srcslot * 8 + kbeg;
    const ushort* gAl = Al + (size_t)(bm + srow) * lda + srcslot * 8 + kbeg;
    const ushort* gBh = Bh + (size_t)(bn + srow) * lda + srcslot * 8 + kbeg;
    const ushort* gBl = Bl + (size_t)(bn + srow) * lda + srcslot * 8 + kbeg;
    ushort* lAh = sAh + 2048 * w;   // wave-uniform LDS bases (+ j*512)
    ushort* lAl = sAl + 2048 * w;
    ushort* lBh = sBh + 2048 * w;
    ushort* lBl = sBl + 2048 * w;

    f32x4 acc[4][4];
    #pragma unroll
    for (int i = 0; i < 4; ++i)
        #pragma unroll
        for (int j = 0; j < 4; ++j)
            acc[i][j] = (f32x4){0.f, 0.f, 0.f, 0.f};

    for (int k0 = 0; k0 < kPerSplit; k0 += 64) {
        #pragma unroll
        for (int j = 0; j < 4; ++j) {
            const size_t go = (size_t)j * 8 * lda + k0;
            gload_lds16(gAh + go, lAh + j * 512);
            gload_lds16(gAl + go, lAl + j * 512);
            gload_lds16(gBh + go, lBh + j * 512);
            gload_lds16(gBl + go, lBl + j * 512);
        }
        __syncthreads();
        #pragma unroll
        for (int sub = 0; sub < 2; ++sub) {
            const int ks  = (sub << 2) | (lane >> 4);        // k-slot 0..7
            const int ssw = ks ^ (l16 & 7);                  // swizzled slot
            bf16x8 fbh[4], fbl[4];
            #pragma unroll
            for (int nj = 0; nj < 4; ++nj) {
                int off = (wc + nj * 16 + l16) * 64 + ssw * 8;
                fbh[nj] = *(const bf16x8*)(sBh + off);
                fbl[nj] = *(const bf16x8*)(sBl + off);
            }
            #pragma unroll
            for (int mi = 0; mi < 4; ++mi) {
                int off = (wr + mi * 16 + l16) * 64 + ssw * 8;
                bf16x8 fah = *(const bf16x8*)(sAh + off);
                bf16x8 fal = *(const bf16x8*)(sAl + off);
                #pragma unroll
                for (int nj = 0; nj < 4; ++nj) {
                    acc[mi][nj] = __builtin_amdgcn_mfma_f32_16x16x32_bf16(fah, fbh[nj], acc[mi][nj], 0, 0, 0);
                    acc[mi][nj] = __builtin_amdgcn_mfma_f32_16x16x32_bf16(fah, fbl[nj], acc[mi][nj], 0, 0, 0);
                    acc[mi][nj] = __builtin_amdgcn_mfma_f32_16x16x32_bf16(fal, fbh[nj], acc[mi][nj], 0, 0, 0);
                }
            }
        }
        __syncthreads();
    }
    // C/D layout: col = lane&15, row = (lane>>4)*4 + reg  [m89-verified]
    #pragma unroll
    for (int nj = 0; nj < 4; ++nj) {
        int col = bn + wc + nj * 16 + l16;
        float bb = bias ? bias[col] : 0.f;
        #pragma unroll
        for (int mi = 0; mi < 4; ++mi) {
            int row0 = bm + wr + mi * 16 + (lane >> 4) * 4;
            #pragma unroll
            for (int r = 0; r < 4; ++r)
                C[(size_t)(row0 + r) * N + col] = acc[mi][nj][r] + bb;
        }
    }
}

// ---------------------------------------------------------------------------
// out[M,D] = part0 + part1 + bias   (split-K combine for gemm2)
// ---------------------------------------------------------------------------
__global__ __launch_bounds__(256)
void combine2(const float* __restrict__ part, const float* __restrict__ ob,
              float* __restrict__ out)
{
    int i = blockIdx.x * 256 + threadIdx.x;        // MM*D_/4
    float4 a = ((const float4*)part)[i];
    float4 b = ((const float4*)(part + (size_t)MM * D_))[i];
    float4 bb = *(const float4*)(ob + ((i & (D_/4 - 1)) << 2));
    float4 o;
    o.x = a.x + b.x + bb.x; o.y = a.y + b.y + bb.y;
    o.z = a.z + b.z + bb.z; o.w = a.w + b.w + bb.w;
    ((float4*)out)[i] = o;
}

// ---------------------------------------------------------------------------
// u = silu(depthwise_conv3(h) + conv_b)  — float4-vectorized along di
// ---------------------------------------------------------------------------
__global__ __launch_bounds__(256)
void conv_silu(const float* __restrict__ h, const float* __restrict__ cw,
               const float* __restrict__ cb, float* __restrict__ u)
{
    size_t i4 = ((size_t)blockIdx.x * 256 + threadIdx.x) << 2;   // elem index
    int    di = (int)(i4 & (DI_ - 1));
    int    l  = (int)((i4 >> 11) & (L_ - 1));
    float4 cc = *(const float4*)(h + i4);
    float4 lf = make_float4(0.f, 0.f, 0.f, 0.f);
    float4 rt = make_float4(0.f, 0.f, 0.f, 0.f);
    if (l > 0)      lf = *(const float4*)(h + i4 - DI_);
    if (l < L_ - 1) rt = *(const float4*)(h + i4 + DI_);
    float4 bb = *(const float4*)(cb + di);
    float cin[4]  = {cc.x, cc.y, cc.z, cc.w};
    float lin[4]  = {lf.x, lf.y, lf.z, lf.w};
    float rin[4]  = {rt.x, rt.y, rt.z, rt.w};
    float bin[4]  = {bb.x, bb.y, bb.z, bb.w};
    float res[4];
    #pragma unroll
    for (int j = 0; j < 4; ++j) {
        const float* w = cw + (size_t)(di + j) * 3;
        float s = bin[j] + lin[j] * w[0] + cin[j] * w[1] + rin[j] * w[2];
        res[j] = s / (1.f + __expf(-s));
    }
    *(float4*)(u + i4) = make_float4(res[0], res[1], res[2], res[3]);
}

// ---------------------------------------------------------------------------
// xproj stage A: partial[s][m][c] = sum_{k in slice s} u[m][k]*xw[c][k]
// ---------------------------------------------------------------------------
__global__ __launch_bounds__(256)
void xprojA(const float* __restrict__ u, const float* __restrict__ xw,
            float* __restrict__ part)
{
    __shared__ float ut[32][132];
    __shared__ float wt[80][132];
    const int t  = threadIdx.x;
    const int bm = blockIdx.x * 32;
    const int ks = blockIdx.y;
    const int r2 = t & 15, cg = t >> 4;
    float acc[2][5] = {};
    for (int ch = 0; ch < 2; ++ch) {
        const int kb = ks * 256 + ch * 128;
        {
            int sr = t >> 3, k4 = (t & 7) * 4;
            #pragma unroll
            for (int i = 0; i < 4; ++i) {
                float4 v = *(const float4*)(u + (size_t)(bm + sr) * DI_ + kb + k4 + 32 * i);
                ut[sr][k4 + 32*i + 0] = v.x; ut[sr][k4 + 32*i + 1] = v.y;
                ut[sr][k4 + 32*i + 2] = v.z; ut[sr][k4 + 32*i + 3] = v.w;
            }
        }
        #pragma unroll
        for (int i = 0; i < 10; ++i) {
            int idx = t + 256 * i;
            int wrow = idx >> 5, k4 = (idx & 31) * 4;
            float4 v = *(const float4*)(xw + (size_t)wrow * DI_ + kb + k4);
            wt[wrow][k4 + 0] = v.x; wt[wrow][k4 + 1] = v.y;
            wt[wrow][k4 + 2] = v.z; wt[wrow][k4 + 3] = v.w;
        }
        __syncthreads();
        for (int k = 0; k < 128; k += 4) {
            float4 u0 = *(const float4*)&ut[r2][k];
            float4 u1 = *(const float4*)&ut[r2 + 16][k];
            #pragma unroll
            for (int c = 0; c < 5; ++c) {
                float4 wv = *(const float4*)&wt[cg * 5 + c][k];
                acc[0][c] = fmaf(u0.x, wv.x, fmaf(u0.y, wv.y, fmaf(u0.z, wv.z, fmaf(u0.w, wv.w, acc[0][c]))));
                acc[1][c] = fmaf(u1.x, wv.x, fmaf(u1.y, wv.y, fmaf(u1.z, wv.z, fmaf(u1.w, wv.w, acc[1][c]))));
            }
        }
        __syncthreads();
    }
    size_t b0 = ((size_t)ks * MM + bm + r2) * 80 + cg * 5;
    size_t b1 = ((size_t)ks * MM + bm + r2 + 16) * 80 + cg * 5;
    #pragma unroll
    for (int c = 0; c < 5; ++c) { part[b0 + c] = acc[0][c]; part[b1 + c] = acc[1][c]; }
}

__global__ __launch_bounds__(256)
void xprojB(const float* __restrict__ part, const float* __restrict__ xpb,
            float* __restrict__ xdbl)
{
    int idx = blockIdx.x * 256 + threadIdx.x;   // MM*80
    int c = idx % 80;
    float s = xpb[c];
    #pragma unroll
    for (int sl = 0; sl < XKS; ++sl)
        s += part[(size_t)sl * (MM * 80) + idx];
    xdbl[idx] = s;
}

__global__ __launch_bounds__(256)
void transpose_dtw(const float* __restrict__ dtw, float* __restrict__ dtwT)
{
    int idx = blockIdx.x * 256 + threadIdx.x;   // RR*DI
    int di  = idx & (DI_ - 1);
    int r   = idx >> 11;
    dtwT[(size_t)r * DI_ + di] = dtw[(size_t)di * RR + r];
}

// ---------------------------------------------------------------------------
// delta[M,DI] = softplus(xdbl[:, :64] @ dtwT + dt_b)
// Round 11: log1pf (libm, ~100 inst) -> __logf(1+t) (v_log_f32, ~2 inst).
// exp(-|x|) in (0,1] so log argument in (1,2]: fast log is well-conditioned,
// abs error ~1e-7 << 2e-3 threshold.
// ---------------------------------------------------------------------------
__global__ __launch_bounds__(256)
void delta_gemm(const float* __restrict__ xdbl, const float* __restrict__ dtwT,
                const float* __restrict__ dtb, float* __restrict__ delta)
{
    __shared__ float dl[16][64];
    const int t    = threadIdx.x;
    const int row0 = blockIdx.y * 16;
    const int col  = blockIdx.x * 256 + t;
    {
        int sr = t >> 4, sk = (t & 15) << 2;
        float4 v = *(const float4*)(xdbl + (size_t)(row0 + sr) * 80 + sk);
        dl[sr][sk] = v.x; dl[sr][sk+1] = v.y; dl[sr][sk+2] = v.z; dl[sr][sk+3] = v.w;
    }
    __syncthreads();
    float acc[16] = {};
    for (int k = 0; k < 64; ++k) {
        float w = dtwT[(size_t)k * DI_ + col];
        #pragma unroll
        for (int rr = 0; rr < 16; ++rr)
            acc[rr] = fmaf(dl[rr][k], w, acc[rr]);
    }
    float bias = dtb[col];
    #pragma unroll
    for (int rr = 0; rr < 16; ++rr) {
        float x  = acc[rr] + bias;
        float sp = fmaxf(x, 0.f) + __logf(1.f + __expf(-fabsf(x)));   // fast softplus
        delta[(size_t)(row0 + rr) * DI_ + col] = sp;
    }
}

// ---------------------------------------------------------------------------
// Scan pass A (2 threads per (b,ch,di): 8 states each)
// ---------------------------------------------------------------------------
__global__ __launch_bounds__(256)
void scanA(const float* __restrict__ delta, const float* __restrict__ u,
           const float* __restrict__ xdbl, const float* __restrict__ A_log,
           float* __restrict__ Pbuf, float* __restrict__ Sbuf)
{
    const int tid  = blockIdx.x * 256 + threadIdx.x;   // B*NC*DI*2
    const int half = tid & 1;
    const int di   = (tid >> 1) & (DI_ - 1);
    const int rest = tid >> 12;
    const int ch   = rest & (NC - 1);
    const int b    = rest >> 6;
    float A2[8];
    {
        const float4* ap = (const float4*)(A_log + (size_t)di * NS + half * 8);
        #pragma unroll
        for (int q = 0; q < 2; ++q) {
            float4 v = ap[q];
            A2[q*4+0] = -__expf(v.x) * 1.44269504f;
            A2[q*4+1] = -__expf(v.y) * 1.44269504f;
            A2[q*4+2] = -__expf(v.z) * 1.44269504f;
            A2[q*4+3] = -__expf(v.w) * 1.44269504f;
        }
    }
    float c[8], P[8];
    #pragma unroll
    for (int n = 0; n < 8; ++n) { c[n] = 0.f; P[n] = 1.f; }
    const size_t l0 = (size_t)b * L_ + (size_t)ch * CL;
    const float* dp = delta + l0 * DI_ + di;
    const float* up = u     + l0 * DI_ + di;
    const float* xp = xdbl  + l0 * 80 + RR + half * 8;
    for (int l = 0; l < CL; ++l) {
        float dlt = dp[(size_t)l * DI_];
        float du  = dlt * up[(size_t)l * DI_];
        const float4* bp = (const float4*)(xp + (size_t)l * 80);
        #pragma unroll
        for (int q = 0; q < 2; ++q) {
            float4 bv = bp[q];
            float bn_[4] = {bv.x, bv.y, bv.z, bv.w};
            #pragma unroll
            for (int j = 0; j < 4; ++j) {
                int   n = q * 4 + j;
                float a = exp2f(dlt * A2[n]);
                c[n] = fmaf(a, c[n], du * bn_[j]);
                P[n] *= a;
            }
        }
    }
    const size_t base = ((size_t)(b * NC + ch) * DI_ + di) * NS + half * 8;
    float4* Pp = (float4*)(Pbuf + base);
    float4* Sp = (float4*)(Sbuf + base);
    #pragma unroll
    for (int q = 0; q < 2; ++q) {
        Pp[q] = make_float4(P[q*4], P[q*4+1], P[q*4+2], P[q*4+3]);
        Sp[q] = make_float4(c[q*4], c[q*4+1], c[q*4+2], c[q*4+3]);
    }
}

__global__ __launch_bounds__(256)
void scanB(const float* __restrict__ Pbuf, const float* __restrict__ Sbuf,
           float* __restrict__ start)
{
    const int tid = blockIdx.x * 256 + threadIdx.x;   // B*DI*NS
    const int n   = tid & (NS - 1);
    const int di  = (tid >> 4) & (DI_ - 1);
    const int b   = tid >> 15;
    float c = 0.f;
    for (int ch = 0; ch < NC; ++ch) {
        size_t idx = ((size_t)(b * NC + ch) * DI_ + di) * NS + n;
        start[idx] = c;
        c = fmaf(Pbuf[idx], c, Sbuf[idx]);
    }
}

// ---------------------------------------------------------------------------
// Scan pass C (2 threads per (b,ch,di)): replay; pairwise shfl for state sum
// ---------------------------------------------------------------------------
__global__ __launch_bounds__(256)
void scanC(const float* __restrict__ delta, const float* __restrict__ u,
           const float* __restrict__ xdbl, const float* __restrict__ A_log,
           const float* __restrict__ Dp, const float* __restrict__ start,
           ushort* __restrict__ yh, ushort* __restrict__ yl)
{
    const int tid  = blockIdx.x * 256 + threadIdx.x;   // B*NC*DI*2
    const int half = tid & 1;
    const int di   = (tid >> 1) & (DI_ - 1);
    const int rest = tid >> 12;
    const int ch   = rest & (NC - 1);
    const int b    = rest >> 6;
    float A2[8];
    {
        const float4* ap = (const float4*)(A_log + (size_t)di * NS + half * 8);
        #pragma unroll
        for (int q = 0; q < 2; ++q) {
            float4 v = ap[q];
            A2[q*4+0] = -__expf(v.x) * 1.44269504f;
            A2[q*4+1] = -__expf(v.y) * 1.44269504f;
            A2[q*4+2] = -__expf(v.z) * 1.44269504f;
            A2[q*4+3] = -__expf(v.w) * 1.44269504f;
        }
    }
    float c[8];
    {
        const size_t base = ((size_t)(b * NC + ch) * DI_ + di) * NS + half * 8;
        const float4* sp = (const float4*)(start + base);
        #pragma unroll
        for (int q = 0; q < 2; ++q) {
            float4 v = sp[q];
            c[q*4+0] = v.x; c[q*4+1] = v.y; c[q*4+2] = v.z; c[q*4+3] = v.w;
        }
    }
    const float Dpar = Dp[di];
    const size_t l0 = (size_t)b * L_ + (size_t)ch * CL;
    const float* dp = delta + l0 * DI_ + di;
    const float* up = u     + l0 * DI_ + di;
    const float* xp = xdbl  + l0 * 80 + RR + half * 8;
    for (int l = 0; l < CL; ++l) {
        float dlt = dp[(size_t)l * DI_];
        float uu  = up[(size_t)l * DI_];
        float du  = dlt * uu;
        const float4* bp = (const float4*)(xp + (size_t)l * 80);
        float sum = 0.f;
        #pragma unroll
        for (int q = 0; q < 2; ++q) {
            float4 bv = bp[q];
            float bn_[4] = {bv.x, bv.y, bv.z, bv.w};
            #pragma unroll
            for (int j = 0; j < 4; ++j) {
                int   n = q * 4 + j;
                float a = exp2f(dlt * A2[n]);
                c[n] = fmaf(a, c[n], du * bn_[j]);
                sum += c[n];
            }
        }
        float tot = sum + __shfl_xor(sum, 1);       // partner has other 8 states
        if (!half) {
            float y = tot + uu * Dpar;
            ushort hb = f2bf_rn(y);
            size_t oi = (l0 + l) * DI_ + di;
            yh[oi] = hb;
            yl[oi] = f2bf_rn(y - bf2f(hb));
        }
    }
}

// ---------------------------------------------------------------------------
extern "C" void kernel_launch(void* const* d_in, const int* in_sizes, int n_in,
                              void* d_out, int out_size, void* d_ws, size_t ws_size,
                              hipStream_t stream)
{
    const float* x      = (const float*)d_in[0];
    const float* in_w   = (const float*)d_in[1];
    const float* in_b   = (const float*)d_in[2];
    const float* conv_w = (const float*)d_in[3];
    const float* conv_b = (const float*)d_in[4];
    const float* xpw    = (const float*)d_in[5];
    const float* xpb    = (const float*)d_in[6];
    const float* dt_w   = (const float*)d_in[7];
    const float* dt_b   = (const float*)d_in[8];
    const float* A_log  = (const float*)d_in[9];
    const float* Dpar   = (const float*)d_in[10];
    const float* out_w  = (const float*)d_in[11];
    const float* out_b  = (const float*)d_in[12];
    float*       out    = (float*)d_out;

    char* ws  = (char*)d_ws;
    size_t off = 0;
    auto alloc = [&](size_t bytes) {
        void* p = ws + off; off = (off + bytes + 255) & ~(size_t)255; return p;
    };
    float*  u_    = (float*)alloc((size_t)MM * DI_ * 4);   // u; later gemm2 partials
    float*  h_    = (float*)alloc((size_t)MM * DI_ * 4);   // h -> delta
    float*  xdbl  = (float*)alloc((size_t)MM * 80 * 4);
    float*  dtwT  = (float*)alloc((size_t)RR * DI_ * 4);
    ushort* yh    = (ushort*)alloc((size_t)MM * DI_ * 2);  // aliases: xpart, Pbuf (16.8MB)
    ushort* yl    = (ushort*)alloc((size_t)MM * DI_ * 2);  // aliases: Sbuf (16.8MB)
    ushort* xh    = (ushort*)alloc((size_t)MM * D_ * 2);   // dead after gemm1
    ushort* xl    = (ushort*)alloc((size_t)MM * D_ * 2);   //   -> stbuf aliases xh+xl
    ushort* wih   = (ushort*)alloc((size_t)DI_ * D_ * 2);
    ushort* wil   = (ushort*)alloc((size_t)DI_ * D_ * 2);
    ushort* woh   = (ushort*)alloc((size_t)D_ * DI_ * 2);
    ushort* wol   = (ushort*)alloc((size_t)D_ * DI_ * 2);
    float*  xpart = (float*)yh;     // 10.5 MB <= 16.8 MB
    float*  Pbuf  = (float*)yh;     // NC=64: B*NC*DI*NS*4 = 16.8 MB (exact fit)
    float*  Sbuf  = (float*)yl;
    float*  stbuf = (float*)xh;     // 16.8 MB spans xh+xl (both dead after gemm1)
    float*  part2 = u_;             // gemm2 split-K partials (2x16.8 = 33.6 MB)

    // 0. bf16 hi/lo conversions
    cvt_hilo<<<(MM * D_ / 4 + 255) / 256, 256, 0, stream>>>(x, xh, xl, MM * D_ / 4);
    cvt_hilo<<<(DI_ * D_ / 4 + 255) / 256, 256, 0, stream>>>(in_w, wih, wil, DI_ * D_ / 4);
    cvt_hilo<<<(D_ * DI_ / 4 + 255) / 256, 256, 0, stream>>>(out_w, woh, wol, D_ * DI_ / 4);
    // 1. h = x @ in_w^T + in_b   [4096 x 2048], K=1024 (16 K-steps of 64)
    gemm_bf16x3<<<dim3(DI_ / 128, MM / 128, 1), 256, 0, stream>>>(
        xh, xl, wih, wil, in_b, h_, D_, DI_, D_);
    // 2. u = silu(conv3(h) + conv_b)
    conv_silu<<<(MM * DI_ / 4) / 256, 256, 0, stream>>>(h_, conv_w, conv_b, u_);
    // 3. x_dbl = u @ x_proj_w^T + x_proj_b  (split-K two-stage)
    xprojA<<<dim3(MM / 32, XKS), 256, 0, stream>>>(u_, xpw, xpart);
    xprojB<<<(MM * 80) / 256, 256, 0, stream>>>(xpart, xpb, xdbl);
    // 4. dt_w transpose
    transpose_dtw<<<(RR * DI_) / 256, 256, 0, stream>>>(dt_w, dtwT);
    // 5. delta = softplus(delta_lr @ dt_w^T + dt_b)  -> h_
    delta_gemm<<<dim3(DI_ / 256, MM / 16), 256, 0, stream>>>(xdbl, dtwT, dt_b, h_);
    // 6-8. chunked selective scan (NC=64, 2 threads/di); y as bf16 hi/lo
    scanA<<<(B_ * NC * DI_ * 2) / 256, 256, 0, stream>>>(h_, u_, xdbl, A_log, Pbuf, Sbuf);
    scanB<<<(B_ * DI_ * NS) / 256, 256, 0, stream>>>(Pbuf, Sbuf, stbuf);
    scanC<<<(B_ * NC * DI_ * 2) / 256, 256, 0, stream>>>(h_, u_, xdbl, A_log, Dpar, stbuf, yh, yl);
    // 9. out = y @ out_w^T + out_b  [4096 x 1024], K=2048, split-K=2 (16 K-steps)
    gemm_bf16x3<<<dim3(D_ / 128, MM / 128, 2), 256, 0, stream>>>(
        yh, yl, woh, wol, nullptr, part2, DI_, D_, DI_ / 2);
    combine2<<<(MM * D_ / 4) / 256, 256, 0, stream>>>(part2, out_b, out);
}